// Round 1
// baseline (337.758 us; speedup 1.0000x reference)
//
#include <hip/hip_runtime.h>

#define E 300
#define P 5
#define H 200
#define S 256
#define L 34
#define B 8
#define NI 254   // pivot positions i = 1..254

// ws layout (in floats)
#define TOK_OFF   0
#define TOK_SZ    (B*S*E)            // 614400
#define WR_OFF    (TOK_OFF+TOK_SZ)   // 614400
#define WR_SZ     (H*900)            // 180000
#define FCWT_OFF  (WR_OFF+WR_SZ)     // 794400
#define FCWT_SZ   (1300*L)           // 44200
#define CT_OFF    (FCWT_OFF+FCWT_SZ) // 838600
#define CT_SZ     (B*S*H)            // 409600
#define POOL_OFF  (CT_OFF+CT_SZ)     // 1248200
#define POOL_SZ   (B*NI*400)         // 812800
// total = 2,061,000 floats = 8.25 MB ws

// ---------------- Kernel A: embedding gather (float4) ----------------
__global__ __launch_bounds__(256) void k_gather(const int* __restrict__ ids,
                                                const float* __restrict__ we,
                                                float* __restrict__ tok) {
    int idx = blockIdx.x * 256 + threadIdx.x;      // float4 index
    const int total4 = B * S * (E / 4);            // 153600
    if (idx >= total4) return;
    int row = idx / 75;                            // (b,s) flat row
    int col = idx - row * 75;
    int id = ids[row];
    const float4* src = (const float4*)we;         // rows of 75 float4 (1200B, 16B-aligned)
    ((float4*)tok)[idx] = src[id * 75 + col];
}

// ---------------- Kernel E: weight repacks ----------------
// Wr[h][kk], kk = k*300 + e  (so a window [tok[j-1],tok[j],tok[j+1]] dots contiguously)
// fcWt[k][l] transpose for coalesced FC reads
__global__ __launch_bounds__(256) void k_repack(const float* __restrict__ convW,
                                                const float* __restrict__ fcW,
                                                float* __restrict__ Wr,
                                                float* __restrict__ fcWt) {
    int idx = blockIdx.x * 256 + threadIdx.x;
    if (idx < WR_SZ) {
        int h = idx / 900;
        int kk = idx - h * 900;
        int k = kk / 300;
        int e = kk - k * 300;
        Wr[idx] = convW[h * 915 + e * 3 + k];      // conv_W[h, e, k], e < E
    }
    if (idx < FCWT_SZ) {
        int k = idx / L;
        int l = idx - k * L;
        fcWt[idx] = fcW[l * 1300 + k];
    }
}

// ---------------- Kernel B: conv_tok GEMM -> ct[b][j][h] (+bias) ----------------
// block = (b, j-tile of 8); thread t -> h = t (<200). K-loop: 3 taps x 75 float4.
__global__ __launch_bounds__(256) void k_conv(const float* __restrict__ tok,
                                              const float* __restrict__ Wr,
                                              const float* __restrict__ convB,
                                              float* __restrict__ ct) {
    __shared__ float4 win4[10 * 75];               // rows j0-1 .. j0+8, 300 floats each
    int bid = blockIdx.x;                          // 0..255
    int b  = bid >> 5;
    int jt = bid & 31;
    int j0 = jt * 8;
    int tid = threadIdx.x;

    const float4* tok4 = (const float4*)tok + (size_t)b * (S * 75);
    for (int idx = tid; idx < 750; idx += 256) {
        int r = idx / 75;
        int c = idx - r * 75;
        int row = j0 - 1 + r;
        float4 v = make_float4(0.f, 0.f, 0.f, 0.f);
        if (row >= 0 && row < S) v = tok4[row * 75 + c];
        win4[idx] = v;
    }
    __syncthreads();

    int h = tid;
    if (h >= H) return;

    float acc[8];
    float bb = convB[h];
#pragma unroll
    for (int jj = 0; jj < 8; jj++) acc[jj] = bb;

    const float4* wr4 = (const float4*)Wr + (size_t)h * 225;
#pragma unroll 1
    for (int k = 0; k < 3; k++) {
        for (int e4 = 0; e4 < 75; e4++) {
            float4 w = wr4[k * 75 + e4];
#pragma unroll
            for (int jj = 0; jj < 8; jj++) {
                float4 x = win4[(jj + k) * 75 + e4];   // broadcast across lanes
                acc[jj] += w.x * x.x + w.y * x.y + w.z * x.z + w.w * x.w;
            }
        }
    }
    float* ctp = ct + (size_t)b * (S * H) + j0 * H + h;
#pragma unroll
    for (int jj = 0; jj < 8; jj++) ctp[jj * H] = acc[jj];
}

// ---------------- Kernel C: dynamic max pooling ----------------
// grid = (254, 2): block handles pivot m (i = m+1) and 4 batches; thread = h.
// cp[h,j] (conv_pf) recomputed from LDS-staged pf rows; uniform j<i branch.
__global__ __launch_bounds__(256) void k_pool(const float* __restrict__ ct,
                                              const float* __restrict__ convW,
                                              const float* __restrict__ pfEmb,
                                              float* __restrict__ pool) {
    __shared__ float pfp[258 * 5];                 // row r = pf position (r-1), zero-padded ends
    int m = blockIdx.x;                            // 0..253
    int p = m + 1;                                 // pivot i
    int b0 = blockIdx.y * 4;
    int tid = threadIdx.x;

    for (int idx = tid; idx < 258 * 5; idx += 256) {
        int r = idx / 5;
        int c = idx - r * 5;
        int jj = r - 1;
        float v = 0.f;
        if (jj >= 0 && jj < S) {
            int d = jj - p; if (d < 0) d = -d;
            v = pfEmb[d * P + c];
        }
        pfp[idx] = v;
    }
    __syncthreads();

    int h = tid;
    if (h >= H) return;

    float wk[3][5];
#pragma unroll
    for (int k = 0; k < 3; k++)
#pragma unroll
        for (int q = 0; q < 5; q++)
            wk[k][q] = convW[h * 915 + (E + q) * 3 + k];

    float accL[4], accR[4];
#pragma unroll
    for (int b = 0; b < 4; b++) { accL[b] = 0.f; accR[b] = 0.f; }

    // rolling pf rows j, j+1, j+2 (conv uses pf rows j-1..j+1 -> pfp[j..j+2])
    float r0[5], r1[5], r2[5];
#pragma unroll
    for (int q = 0; q < 5; q++) { r0[q] = pfp[q]; r1[q] = pfp[5 + q]; r2[q] = pfp[10 + q]; }

    const float* ctb = ct + (size_t)b0 * (S * H) + h;
    for (int j = 0; j < S; j++) {
        float cp = 0.f;
#pragma unroll
        for (int q = 0; q < 5; q++)
            cp += wk[0][q] * r0[q] + wk[1][q] * r1[q] + wk[2][q] * r2[q];
        const float* cp0 = ctb + j * H;
        if (j < p) {
#pragma unroll
            for (int b = 0; b < 4; b++) {
                float v = cp0[b * (S * H)] + cp;
                accL[b] = fmaxf(accL[b], v);
            }
        } else {
#pragma unroll
            for (int b = 0; b < 4; b++) {
                float v = cp0[b * (S * H)] + cp;
                accR[b] = fmaxf(accR[b], v);
            }
        }
#pragma unroll
        for (int q = 0; q < 5; q++) { r0[q] = r1[q]; r1[q] = r2[q]; }
        if (j + 3 < 258) {
#pragma unroll
            for (int q = 0; q < 5; q++) r2[q] = pfp[(j + 3) * 5 + q];
        }
    }

    float* pb = pool + ((size_t)b0 * NI + m) * 400 + h;
#pragma unroll
    for (int b = 0; b < 4; b++) {
        pb[(size_t)b * (NI * 400)] = accL[b];          // max_left  -> f in [0,200)
        pb[(size_t)b * (NI * 400) + 200] = accR[b];    // max_right -> f in [200,400)
    }
}

// ---------------- Kernel D: final FC + end padding ----------------
// thread = one output (b,s,l). feat = [poolL|poolR|tok[m],tok[m+1],tok[m+2]] (llf is
// contiguous 900 floats in tok). fcWt is [k][l] so lanes read coalesced.
__global__ __launch_bounds__(256) void k_fc(const float* __restrict__ pool,
                                            const float* __restrict__ tok,
                                            const float* __restrict__ fcWt,
                                            const float* __restrict__ fcB,
                                            float* __restrict__ out) {
    int idx = blockIdx.x * 256 + threadIdx.x;
    const int total = B * S * L;                   // 69632
    if (idx >= total) return;
    int b = idx / (S * L);
    int rem = idx - b * (S * L);
    int s = rem / L;
    int l = rem - s * L;

    float val;
    if (s == 0 || s == S - 1) {
        val = (l == L - 1) ? 1.0f : 0.0f;
    } else {
        int m = s - 1;
        const float* pl = pool + ((size_t)b * NI + m) * 400;
        const float* fw = fcWt + l;
        float a0 = fcB[l], a1 = 0.f, a2 = 0.f, a3 = 0.f;
#pragma unroll 1
        for (int k = 0; k < 400; k += 4) {
            a0 += fw[(k + 0) * L] * pl[k + 0];
            a1 += fw[(k + 1) * L] * pl[k + 1];
            a2 += fw[(k + 2) * L] * pl[k + 2];
            a3 += fw[(k + 3) * L] * pl[k + 3];
        }
        const float* tk = tok + (size_t)b * (S * E) + m * E;  // 900 contiguous floats
        const float* fw2 = fcWt + 400 * L + l;
#pragma unroll 1
        for (int k = 0; k < 900; k += 4) {
            a0 += fw2[(k + 0) * L] * tk[k + 0];
            a1 += fw2[(k + 1) * L] * tk[k + 1];
            a2 += fw2[(k + 2) * L] * tk[k + 2];
            a3 += fw2[(k + 3) * L] * tk[k + 3];
        }
        val = (a0 + a1) + (a2 + a3);
    }
    out[idx] = val;
}

extern "C" void kernel_launch(void* const* d_in, const int* in_sizes, int n_in,
                              void* d_out, int out_size, void* d_ws, size_t ws_size,
                              hipStream_t stream) {
    const int*   ids      = (const int*)d_in[0];
    const float* word_emb = (const float*)d_in[1];
    const float* pf_emb   = (const float*)d_in[2];
    const float* conv_W   = (const float*)d_in[3];
    const float* conv_b   = (const float*)d_in[4];
    const float* fc_W     = (const float*)d_in[5];
    const float* fc_b     = (const float*)d_in[6];
    float* out = (float*)d_out;
    float* ws  = (float*)d_ws;

    float* tok  = ws + TOK_OFF;
    float* Wr   = ws + WR_OFF;
    float* fcWt = ws + FCWT_OFF;
    float* ct   = ws + CT_OFF;
    float* pool = ws + POOL_OFF;

    k_gather<<<600, 256, 0, stream>>>(ids, word_emb, tok);
    k_repack<<<704, 256, 0, stream>>>(conv_W, fc_W, Wr, fcWt);
    k_conv<<<256, 256, 0, stream>>>(tok, Wr, conv_b, ct);
    k_pool<<<dim3(254, 2), 256, 0, stream>>>(ct, conv_W, pf_emb, pool);
    k_fc<<<272, 256, 0, stream>>>(pool, tok, fcWt, fc_b, out);
}

// Round 2
// 199.898 us; speedup vs baseline: 1.6896x; 1.6896x over previous
//
#include <hip/hip_runtime.h>

#define E 300
#define P 5
#define H 200
#define S 256
#define L 34
#define B 8
#define NI 254   // pivot positions i = 1..254

// ws layout (floats)
#define TOKP_OFF  0
#define TOKP_SZ   (B*258*300)          // 619200  (padded: row0 & row257 zero)
#define WR2_OFF   (TOKP_OFF+TOKP_SZ)   // 619200
#define WR2_SZ    (900*H)              // 180000  Wr2[k*300+e][h]
#define FCWT_OFF  (WR2_OFF+WR2_SZ)     // 799200
#define FCWT_SZ   (1300*L)             // 44200   fcWt[k][l]
#define CT_OFF    (FCWT_OFF+FCWT_SZ)   // 843400
#define CT_SZ     (B*S*H)              // 409600  ct[b][j][h]
#define POOL_OFF  (CT_OFF+CT_SZ)       // 1253000
#define POOL_SZ   (B*NI*400)           // 812800
#define G_OFF     (POOL_OFF+POOL_SZ)   // 2065800
#define G_SZ      (512*H)              // 102400  g[t2][h], t2 = (j-i)+256
#define C0_OFF    (G_OFF+G_SZ)         // 2168200
#define C0_SZ     (NI*H)               // 50800   conv_pf at j=0 per pivot
#define C255_OFF  (C0_OFF+C0_SZ)       // 2219000
#define C255_SZ   (NI*H)               // 50800
#define POOLP_OFF (C255_OFF+C255_SZ)   // 2269800
#define POOLP_SZ  (4*B*256*400)        // 3276800 poolp[jc][b][m256][400]
#define FCP_OFF   (POOLP_OFF+POOLP_SZ) // 5546600
#define FCP_SZ    (4*B*S*L)            // 278528
// total 5,825,128 floats = 23.3 MB

__device__ __forceinline__ float4 add4(float4 a, float4 b) {
    return make_float4(a.x+b.x, a.y+b.y, a.z+b.z, a.w+b.w);
}
__device__ __forceinline__ float4 max4(float4 a, float4 b) {
    return make_float4(fmaxf(a.x,b.x), fmaxf(a.y,b.y), fmaxf(a.z,b.z), fmaxf(a.w,b.w));
}

// ---------------- A: embedding gather into padded tokp[b][258][300] ----------------
__global__ __launch_bounds__(256) void k_gather(const int* __restrict__ ids,
                                                const float* __restrict__ we,
                                                float* __restrict__ tokp) {
    int idx = blockIdx.x * 256 + threadIdx.x;      // float4 index
    const int total4 = B * 258 * 75;               // 154800
    if (idx >= total4) return;
    int row = idx / 75;
    int col = idx - row * 75;
    int b = row / 258;
    int r = row - b * 258;
    float4 v = make_float4(0.f, 0.f, 0.f, 0.f);
    if (r >= 1 && r <= 256) {
        int id = ids[b * S + (r - 1)];
        v = ((const float4*)we)[(size_t)id * 75 + col];
    }
    ((float4*)tokp)[idx] = v;
}

// ---------------- B: weight repacks ----------------
// Wr2[(k*300+e)*200 + h] = conv_W[h, e, k]  (lane-h coalesced in k_conv)
// fcWt[k*34 + l] = fc_W[l, k]
__global__ __launch_bounds__(256) void k_repack(const float* __restrict__ convW,
                                                const float* __restrict__ fcW,
                                                float* __restrict__ Wr2,
                                                float* __restrict__ fcWt) {
    int idx = blockIdx.x * 256 + threadIdx.x;
    if (idx < WR2_SZ) {
        int kk = idx / H;          // k*300+e
        int h  = idx - kk * H;
        int k  = kk / 300;
        int e  = kk - k * 300;
        Wr2[idx] = convW[h * 915 + e * 3 + k];
    }
    if (idx < FCWT_SZ) {
        int k = idx / L;
        int l = idx - k * L;
        fcWt[idx] = fcW[l * 1300 + k];
    }
}

// ---------------- C: conv_pf tables ----------------
// g[t2][h] = sum_k sum_q W_pf[h,q,k] * pf_emb[|d+k-1|, q],  d = t2-256  (middle j)
// c0[m][h]   = conv_pf at j=0   for pivot i=m+1 (tap k=0 dropped)
// c255[m][h] = conv_pf at j=255 for pivot i=m+1 (tap k=2 dropped)
__global__ __launch_bounds__(256) void k_gtab(const float* __restrict__ convW,
                                              const float* __restrict__ pf,
                                              float* __restrict__ g,
                                              float* __restrict__ c0,
                                              float* __restrict__ c255) {
    int idx = blockIdx.x * 256 + threadIdx.x;
    if (idx < 512 * H) {
        int t2 = idx / H, h = idx - t2 * H;
        int d = t2 - 256;
        float a = 0.f;
#pragma unroll
        for (int k = 0; k < 3; k++) {
            int r = d + k - 1; r = (r < 0) ? -r : r; if (r > 255) r = 255;
#pragma unroll
            for (int q = 0; q < P; q++)
                a += convW[h * 915 + (E + q) * 3 + k] * pf[r * P + q];
        }
        g[idx] = a;
    } else if (idx < 512 * H + NI * H) {
        int j = idx - 512 * H;
        int m = j / H, h = j - m * H;
        int i = m + 1;
        float a = 0.f;
#pragma unroll
        for (int q = 0; q < P; q++) {
            a += convW[h * 915 + (E + q) * 3 + 1] * pf[i * P + q];
            a += convW[h * 915 + (E + q) * 3 + 2] * pf[(i - 1) * P + q];
        }
        c0[m * H + h] = a;
    } else if (idx < 512 * H + 2 * NI * H) {
        int j = idx - 512 * H - NI * H;
        int m = j / H, h = j - m * H;
        int i = m + 1;
        float a = 0.f;
#pragma unroll
        for (int q = 0; q < P; q++) {
            a += convW[h * 915 + (E + q) * 3 + 0] * pf[(254 - i) * P + q];
            a += convW[h * 915 + (E + q) * 3 + 1] * pf[(255 - i) * P + q];
        }
        c255[m * H + h] = a;
    }
}

// ---------------- D: conv_tok -> ct[b][j][h] ----------------
// block=(b, j-tile of 8); thread=h. x-window loads are block-uniform (scalarizable);
// weights Wr2 read lane-coalesced b32. No LDS.
__global__ __launch_bounds__(256) void k_conv(const float* __restrict__ tokp,
                                              const float* __restrict__ Wr2,
                                              const float* __restrict__ convB,
                                              float* __restrict__ ct) {
    int bid = blockIdx.x;
    int b  = bid >> 5;
    int jt = bid & 31;
    int j0 = jt * 8;
    int h = threadIdx.x;
    if (h >= H) return;

    // tokp row (j0 + r) covers tok row j0-1+r; output j=j0+jj uses rows jj..jj+2
    const float4* x4 = (const float4*)(tokp + (size_t)b * 258 * 300) + (size_t)j0 * 75;

    float acc[8];
#pragma unroll
    for (int jj = 0; jj < 8; jj++) acc[jj] = 0.f;

#pragma unroll 1
    for (int e4 = 0; e4 < 75; e4++) {
        float4 x[10];
#pragma unroll
        for (int r = 0; r < 10; r++) x[r] = x4[r * 75 + e4];
        int e = e4 * 4;
#pragma unroll
        for (int k = 0; k < 3; k++) {
            float w0 = Wr2[(k * 300 + e + 0) * H + h];
            float w1 = Wr2[(k * 300 + e + 1) * H + h];
            float w2 = Wr2[(k * 300 + e + 2) * H + h];
            float w3 = Wr2[(k * 300 + e + 3) * H + h];
#pragma unroll
            for (int jj = 0; jj < 8; jj++) {
                float4 xv = x[jj + k];
                acc[jj] += w0 * xv.x + w1 * xv.y + w2 * xv.z + w3 * xv.w;
            }
        }
    }
    float bb = convB[h];
    float* ctp = ct + ((size_t)b * S + j0) * H + h;
#pragma unroll
    for (int jj = 0; jj < 8; jj++) ctp[jj * H] = acc[jj] + bb;
}

// ---------------- E: pooling phase A (j-chunk partial maxima) ----------------
// grid (64 pivot-groups, 4 j-chunks, 2 batch-groups); 256 thr = 4 batch-subs x 64 lanes
// (50 active, h = 4*lane). Per thread: 4 pivots x {L,R} float4 accumulators.
__global__ __launch_bounds__(256) void k_poolA(const float* __restrict__ ct,
                                               const float* __restrict__ g,
                                               const float* __restrict__ c0,
                                               const float* __restrict__ c255,
                                               float* __restrict__ poolp) {
    int pg = blockIdx.x;           // 0..63
    int jc = blockIdx.y;           // 0..3
    int bg = blockIdx.z;           // 0..1
    int tid = threadIdx.x;
    int sub = tid >> 6;
    int lane = tid & 63;
    if (lane >= 50) return;
    int h = lane << 2;
    int b = bg * 4 + sub;
    int p0 = pg * 4 + 1;           // pivots p0..p0+3 (m = 4*pg..4*pg+3)
    int js = jc * 64, je = js + 63;

    const float* ctb = ct + (size_t)b * S * H + h;   // + j*H
    const float* gb  = g + h;                        // + t2*H

    float4 aL[4], aR[4];
#pragma unroll
    for (int k = 0; k < 4; k++) {
        aL[k] = make_float4(0.f,0.f,0.f,0.f);
        aR[k] = make_float4(0.f,0.f,0.f,0.f);
    }

    if (jc == 0) {                                   // j = 0 (always left)
        float4 c = *(const float4*)(ctb + 0);
#pragma unroll
        for (int k = 0; k < 4; k++) {
            int m = pg * 4 + k;
            if (m < NI) {
                float4 v = add4(c, *(const float4*)(c0 + m * H + h));
                aL[k] = max4(aL[k], v);
            }
        }
    }

    int j1 = (js > 1) ? js : 1;
    int j2 = (je < 254) ? je : 254;
    int eL = (j2 + 1 < p0) ? (j2 + 1) : p0;          // [j1, eL): all-left
    int mS = (j1 > p0) ? j1 : p0;                    // [mS, eM): mixed
    int eM = (j2 + 1 < p0 + 4) ? (j2 + 1) : (p0 + 4);
    int rS = (j1 > p0 + 4) ? j1 : (p0 + 4);          // [rS, j2]: all-right

#pragma unroll 2
    for (int j = j1; j < eL; ++j) {
        float4 c = *(const float4*)(ctb + (size_t)j * H);
#pragma unroll
        for (int k = 0; k < 4; k++) {
            float4 gv = *(const float4*)(gb + (size_t)(j - p0 - k + 256) * H);
            aL[k] = max4(aL[k], add4(c, gv));
        }
    }
    for (int j = mS; j < eM; ++j) {                  // <= 4 iterations
        float4 c = *(const float4*)(ctb + (size_t)j * H);
#pragma unroll
        for (int k = 0; k < 4; k++) {
            float4 gv = *(const float4*)(gb + (size_t)(j - p0 - k + 256) * H);
            float4 v = add4(c, gv);
            if (j < p0 + k) aL[k] = max4(aL[k], v);
            else            aR[k] = max4(aR[k], v);
        }
    }
#pragma unroll 2
    for (int j = rS; j <= j2; ++j) {
        float4 c = *(const float4*)(ctb + (size_t)j * H);
#pragma unroll
        for (int k = 0; k < 4; k++) {
            float4 gv = *(const float4*)(gb + (size_t)(j - p0 - k + 256) * H);
            aR[k] = max4(aR[k], add4(c, gv));
        }
    }

    if (jc == 3) {                                   // j = 255 (always right)
        float4 c = *(const float4*)(ctb + (size_t)255 * H);
#pragma unroll
        for (int k = 0; k < 4; k++) {
            int m = pg * 4 + k;
            if (m < NI) {
                float4 v = add4(c, *(const float4*)(c255 + m * H + h));
                aR[k] = max4(aR[k], v);
            }
        }
    }

    float* pp = poolp + ((size_t)jc * B + b) * 256 * 400;
#pragma unroll
    for (int k = 0; k < 4; k++) {
        int m = pg * 4 + k;
        if (m < NI) {
            *(float4*)(pp + m * 400 + h)       = aL[k];
            *(float4*)(pp + m * 400 + 200 + h) = aR[k];
        }
    }
}

// ---------------- F: pooling phase B (combine j-chunks) ----------------
__global__ __launch_bounds__(256) void k_poolred(const float* __restrict__ poolp,
                                                 float* __restrict__ pool) {
    int idx = blockIdx.x * 256 + threadIdx.x;
    const int total = B * NI * 400;                  // 812800
    if (idx >= total) return;
    int f = idx % 400;
    int t = idx / 400;
    int m = t % NI;
    int b = t / NI;
    float v = 0.f;
#pragma unroll
    for (int jc = 0; jc < 4; jc++)
        v = fmaxf(v, poolp[(((size_t)jc * B + b) * 256 + m) * 400 + f]);
    pool[((size_t)b * NI + m) * 400 + f] = v;
}

// ---------------- G: FC split-K partials ----------------
// grid (272, 4): blockIdx.y = k-split (325 each over global K=1300: 400 pool + 900 llf)
__global__ __launch_bounds__(256) void k_fc1(const float* __restrict__ pool,
                                             const float* __restrict__ tokp,
                                             const float* __restrict__ fcWt,
                                             float* __restrict__ fcp) {
    int o = blockIdx.x * 256 + threadIdx.x;
    const int total = B * S * L;
    if (o >= total) return;
    int ks = blockIdx.y;
    int b = o / (S * L);
    int rem = o - b * (S * L);
    int s = rem / L;
    int l = rem - s * L;
    if (s == 0 || s == S - 1) return;
    int m = s - 1;

    int k0 = ks * 325, k1 = k0 + 325;
    const float* pl = pool + ((size_t)b * NI + m) * 400;
    const float* tk = tokp + ((size_t)b * 258 + m + 1) * 300;  // llf: 900 contiguous
    float a0 = 0.f, a1 = 0.f;

    int pe = (k1 < 400) ? k1 : 400;
#pragma unroll 4
    for (int k = k0; k < pe; ++k) {
        float w = fcWt[k * L + l];
        a0 += w * pl[k];
    }
    int ts = (k0 > 400) ? k0 : 400;
#pragma unroll 4
    for (int k = ts; k < k1; ++k) {
        float w = fcWt[k * L + l];
        a1 += w * tk[k - 400];
    }
    fcp[(size_t)ks * total + o] = a0 + a1;
}

// ---------------- H: FC combine + end padding ----------------
__global__ __launch_bounds__(256) void k_fc2(const float* __restrict__ fcp,
                                             const float* __restrict__ fcB,
                                             float* __restrict__ out) {
    int o = blockIdx.x * 256 + threadIdx.x;
    const int total = B * S * L;
    if (o >= total) return;
    int rem = o % (S * L);
    int s = rem / L;
    int l = rem - s * L;
    float val;
    if (s == 0 || s == S - 1) {
        val = (l == L - 1) ? 1.0f : 0.0f;
    } else {
        val = fcB[l];
#pragma unroll
        for (int ks = 0; ks < 4; ks++)
            val += fcp[(size_t)ks * total + o];
    }
    out[o] = val;
}

extern "C" void kernel_launch(void* const* d_in, const int* in_sizes, int n_in,
                              void* d_out, int out_size, void* d_ws, size_t ws_size,
                              hipStream_t stream) {
    const int*   ids      = (const int*)d_in[0];
    const float* word_emb = (const float*)d_in[1];
    const float* pf_emb   = (const float*)d_in[2];
    const float* conv_W   = (const float*)d_in[3];
    const float* conv_b   = (const float*)d_in[4];
    const float* fc_W     = (const float*)d_in[5];
    const float* fc_b     = (const float*)d_in[6];
    float* out = (float*)d_out;
    float* ws  = (float*)d_ws;

    float* tokp  = ws + TOKP_OFF;
    float* Wr2   = ws + WR2_OFF;
    float* fcWt  = ws + FCWT_OFF;
    float* ct    = ws + CT_OFF;
    float* pool  = ws + POOL_OFF;
    float* g     = ws + G_OFF;
    float* c0    = ws + C0_OFF;
    float* c255  = ws + C255_OFF;
    float* poolp = ws + POOLP_OFF;
    float* fcp   = ws + FCP_OFF;

    k_gather<<<605, 256, 0, stream>>>(ids, word_emb, tokp);
    k_repack<<<704, 256, 0, stream>>>(conv_W, fc_W, Wr2, fcWt);
    k_gtab<<<797, 256, 0, stream>>>(conv_W, pf_emb, g, c0, c255);
    k_conv<<<256, 256, 0, stream>>>(tokp, Wr2, conv_b, ct);
    k_poolA<<<dim3(64, 4, 2), 256, 0, stream>>>(ct, g, c0, c255, poolp);
    k_poolred<<<3175, 256, 0, stream>>>(poolp, pool);
    k_fc1<<<dim3(272, 4), 256, 0, stream>>>(pool, tokp, fcWt, fcp);
    k_fc2<<<272, 256, 0, stream>>>(fcp, fc_b, out);
}

// Round 3
// 183.081 us; speedup vs baseline: 1.8449x; 1.0919x over previous
//
#include <hip/hip_runtime.h>

#define E 300
#define P 5
#define H 200
#define S 256
#define L 34
#define B 8
#define NI 254   // pivot positions i = 1..254

// ws layout (floats)
#define TOKP_OFF  0
#define TOKP_SZ   (B*258*300)          // 619200  (padded: row0 & row257 zero)
#define WR2_OFF   (TOKP_OFF+TOKP_SZ)   // 619200
#define WR2_SZ    (900*H)              // 180000  Wr2[k*300+e][h]
#define FCWT_OFF  (WR2_OFF+WR2_SZ)     // 799200
#define FCWT_SZ   (1300*L)             // 44200   fcWt[k][l]
#define CT_OFF    (FCWT_OFF+FCWT_SZ)   // 843400
#define CT_SZ     (B*S*H)              // 409600  ct[b][j][h]
#define POOL_OFF  (CT_OFF+CT_SZ)       // 1253000
#define POOL_SZ   (B*NI*400)           // 812800
#define G_OFF     (POOL_OFF+POOL_SZ)   // 2065800
#define G_SZ      (512*H)              // 102400  g[t2][h], t2 = (j-i)+256
#define C0_OFF    (G_OFF+G_SZ)         // 2168200
#define C0_SZ     (NI*H)               // 50800
#define C255_OFF  (C0_OFF+C0_SZ)       // 2219000
#define C255_SZ   (NI*H)               // 50800
#define POOLP_OFF (C255_OFF+C255_SZ)   // 2269800
#define POOLP_SZ  (2*B*256*400)        // 1638400 poolp[jc][b][m256][400]
#define FCP_OFF   (POOLP_OFF+POOLP_SZ) // 3908200
#define FCP_SZ    (4*B*S*L)            // 278528
// total 4,186,728 floats = 16.7 MB

__device__ __forceinline__ float4 add4(float4 a, float4 b) {
    return make_float4(a.x+b.x, a.y+b.y, a.z+b.z, a.w+b.w);
}
__device__ __forceinline__ float4 max4(float4 a, float4 b) {
    return make_float4(fmaxf(a.x,b.x), fmaxf(a.y,b.y), fmaxf(a.z,b.z), fmaxf(a.w,b.w));
}

// ---------------- A: embedding gather into padded tokp[b][258][300] ----------------
__global__ __launch_bounds__(256) void k_gather(const int* __restrict__ ids,
                                                const float* __restrict__ we,
                                                float* __restrict__ tokp) {
    int idx = blockIdx.x * 256 + threadIdx.x;      // float4 index
    const int total4 = B * 258 * 75;               // 154800
    if (idx >= total4) return;
    int row = idx / 75;
    int col = idx - row * 75;
    int b = row / 258;
    int r = row - b * 258;
    float4 v = make_float4(0.f, 0.f, 0.f, 0.f);
    if (r >= 1 && r <= 256) {
        int id = ids[b * S + (r - 1)];
        v = ((const float4*)we)[(size_t)id * 75 + col];
    }
    ((float4*)tokp)[idx] = v;
}

// ---------------- B: merged prep (weight repacks + conv_pf tables) ----------------
__global__ __launch_bounds__(256) void k_prep(const float* __restrict__ convW,
                                              const float* __restrict__ fcW,
                                              const float* __restrict__ pf,
                                              float* __restrict__ Wr2,
                                              float* __restrict__ fcWt,
                                              float* __restrict__ g,
                                              float* __restrict__ c0,
                                              float* __restrict__ c255) {
    int idx = blockIdx.x * 256 + threadIdx.x;
    if (idx < WR2_SZ) {            // Wr2[(k*300+e)*200+h] = conv_W[h,e,k]
        int kk = idx / H;
        int h  = idx - kk * H;
        int k  = kk / 300;
        int e  = kk - k * 300;
        Wr2[idx] = convW[h * 915 + e * 3 + k];
    }
    if (idx < FCWT_SZ) {           // fcWt[k*34+l] = fc_W[l,k]
        int k = idx / L;
        int l = idx - k * L;
        fcWt[idx] = fcW[l * 1300 + k];
    }
    if (idx < 512 * H) {           // g[t2*H+h], t2 = d+256
        int t2 = idx / H, h = idx - t2 * H;
        int d = t2 - 256;
        float a = 0.f;
#pragma unroll
        for (int k = 0; k < 3; k++) {
            int r = d + k - 1; r = (r < 0) ? -r : r; if (r > 255) r = 255;
#pragma unroll
            for (int q = 0; q < P; q++)
                a += convW[h * 915 + (E + q) * 3 + k] * pf[r * P + q];
        }
        g[idx] = a;
    } else if (idx < 512 * H + NI * H) {     // c0: j=0, tap k=0 dropped
        int j = idx - 512 * H;
        int m = j / H, h = j - m * H;
        int i = m + 1;
        float a = 0.f;
#pragma unroll
        for (int q = 0; q < P; q++) {
            a += convW[h * 915 + (E + q) * 3 + 1] * pf[i * P + q];
            a += convW[h * 915 + (E + q) * 3 + 2] * pf[(i - 1) * P + q];
        }
        c0[m * H + h] = a;
    } else if (idx < 512 * H + 2 * NI * H) { // c255: j=255, tap k=2 dropped
        int j = idx - 512 * H - NI * H;
        int m = j / H, h = j - m * H;
        int i = m + 1;
        float a = 0.f;
#pragma unroll
        for (int q = 0; q < P; q++) {
            a += convW[h * 915 + (E + q) * 3 + 0] * pf[(254 - i) * P + q];
            a += convW[h * 915 + (E + q) * 3 + 1] * pf[(255 - i) * P + q];
        }
        c255[m * H + h] = a;
    }
}

// ---------------- C: conv_tok -> ct[b][j][h] ----------------
// 1024 threads = 4 e-quarters x 256 (thread=h). Each quarter computes a partial
// over ~19 of the 75 float4 e-columns; LDS combine. x-window loads block+quarter
// uniform (scalarized); weights lane-coalesced b32.
__global__ __launch_bounds__(1024) void k_conv(const float* __restrict__ tokp,
                                               const float* __restrict__ Wr2,
                                               const float* __restrict__ convB,
                                               float* __restrict__ ct) {
    __shared__ float lds[4 * 8 * 200];             // 25.6 KB
    int bid = blockIdx.x;
    int b  = bid >> 5;
    int jt = bid & 31;
    int j0 = jt * 8;
    int tid = threadIdx.x;
    int q = tid >> 8;
    int h = tid & 255;

    if (h < H) {
        int e4s = q * 19;
        int e4e = (q < 3) ? e4s + 19 : 75;

        const float4* x4 = (const float4*)(tokp + (size_t)b * 258 * 300) + (size_t)j0 * 75;

        float acc[8];
#pragma unroll
        for (int jj = 0; jj < 8; jj++) acc[jj] = 0.f;

#pragma unroll 1
        for (int e4 = e4s; e4 < e4e; e4++) {
            float4 x[10];
#pragma unroll
            for (int r = 0; r < 10; r++) x[r] = x4[r * 75 + e4];
            int e = e4 * 4;
#pragma unroll
            for (int k = 0; k < 3; k++) {
                float w0 = Wr2[(k * 300 + e + 0) * H + h];
                float w1 = Wr2[(k * 300 + e + 1) * H + h];
                float w2 = Wr2[(k * 300 + e + 2) * H + h];
                float w3 = Wr2[(k * 300 + e + 3) * H + h];
#pragma unroll
                for (int jj = 0; jj < 8; jj++) {
                    float4 xv = x[jj + k];
                    acc[jj] += w0 * xv.x + w1 * xv.y + w2 * xv.z + w3 * xv.w;
                }
            }
        }
#pragma unroll
        for (int jj = 0; jj < 8; jj++) lds[(q * 8 + jj) * 200 + h] = acc[jj];
    }
    __syncthreads();

    for (int idx = tid; idx < 1600; idx += 1024) {
        int jj = idx / 200;
        int hh = idx - jj * 200;
        float v = lds[jj * 200 + hh] + lds[(8 + jj) * 200 + hh]
                + lds[(16 + jj) * 200 + hh] + lds[(24 + jj) * 200 + hh]
                + convB[hh];
        ct[((size_t)b * S + j0 + jj) * H + hh] = v;
    }
}

// ---------------- D: pooling phase A ----------------
// grid (64 pg x 2 jc x 8 b). 256 thr = 4 j-subs x 64 lanes (50 active, h=4*lane).
// Each sub covers 32 j's; LDS max-combine across subs -> poolp[jc] slice.
__global__ __launch_bounds__(256) void k_poolA(const float* __restrict__ ct,
                                               const float* __restrict__ g,
                                               const float* __restrict__ c0,
                                               const float* __restrict__ c255,
                                               float* __restrict__ poolp) {
    __shared__ float4 lds4[4 * 4 * 2 * 50];        // [sub][k][lr][lane] 12.8 KB
    int pg = blockIdx.x;           // 0..63
    int jc = blockIdx.y;           // 0..1
    int b  = blockIdx.z;           // 0..7
    int tid = threadIdx.x;
    int sub = tid >> 6;
    int lane = tid & 63;
    int p0 = pg * 4 + 1;           // pivots p0..p0+3

    if (lane < 50) {
        int h = lane << 2;
        int jbase = jc * 128 + sub * 32;
        const float* ctb = ct + (size_t)b * S * H + h;
        const float* gb  = g + h;

        float4 aL[4], aR[4];
#pragma unroll
        for (int k = 0; k < 4; k++) {
            aL[k] = make_float4(0.f,0.f,0.f,0.f);
            aR[k] = make_float4(0.f,0.f,0.f,0.f);
        }

        if (jc == 0 && sub == 0) {                 // j = 0 (always left)
            float4 c = *(const float4*)(ctb + 0);
#pragma unroll
            for (int k = 0; k < 4; k++) {
                int m = pg * 4 + k;
                if (m < NI) aL[k] = max4(aL[k], add4(c, *(const float4*)(c0 + m * H + h)));
            }
        }

        int j1 = (jbase > 1) ? jbase : 1;
        int j2 = (jbase + 31 < 254) ? (jbase + 31) : 254;
        int eL = (j2 + 1 < p0) ? (j2 + 1) : p0;
        int mS = (j1 > p0) ? j1 : p0;
        int eM = (j2 + 1 < p0 + 4) ? (j2 + 1) : (p0 + 4);
        int rS = (j1 > p0 + 4) ? j1 : (p0 + 4);

#pragma unroll 2
        for (int j = j1; j < eL; ++j) {
            float4 c = *(const float4*)(ctb + (size_t)j * H);
#pragma unroll
            for (int k = 0; k < 4; k++) {
                float4 gv = *(const float4*)(gb + (size_t)(j - p0 - k + 256) * H);
                aL[k] = max4(aL[k], add4(c, gv));
            }
        }
        for (int j = mS; j < eM; ++j) {            // <= 4 iterations
            float4 c = *(const float4*)(ctb + (size_t)j * H);
#pragma unroll
            for (int k = 0; k < 4; k++) {
                float4 gv = *(const float4*)(gb + (size_t)(j - p0 - k + 256) * H);
                float4 v = add4(c, gv);
                if (j < p0 + k) aL[k] = max4(aL[k], v);
                else            aR[k] = max4(aR[k], v);
            }
        }
#pragma unroll 2
        for (int j = rS; j <= j2; ++j) {
            float4 c = *(const float4*)(ctb + (size_t)j * H);
#pragma unroll
            for (int k = 0; k < 4; k++) {
                float4 gv = *(const float4*)(gb + (size_t)(j - p0 - k + 256) * H);
                aR[k] = max4(aR[k], add4(c, gv));
            }
        }

        if (jc == 1 && sub == 3) {                 // j = 255 (always right)
            float4 c = *(const float4*)(ctb + (size_t)255 * H);
#pragma unroll
            for (int k = 0; k < 4; k++) {
                int m = pg * 4 + k;
                if (m < NI) aR[k] = max4(aR[k], add4(c, *(const float4*)(c255 + m * H + h)));
            }
        }

#pragma unroll
        for (int k = 0; k < 4; k++) {
            lds4[((sub * 4 + k) * 2 + 0) * 50 + lane] = aL[k];
            lds4[((sub * 4 + k) * 2 + 1) * 50 + lane] = aR[k];
        }
    }
    __syncthreads();

    for (int idx = tid; idx < 400; idx += 256) {
        int k = idx / 100;
        int r = idx - k * 100;
        int lr = r / 50;
        int ln = r - lr * 50;
        float4 v = lds4[((0 * 4 + k) * 2 + lr) * 50 + ln];
        v = max4(v, lds4[((1 * 4 + k) * 2 + lr) * 50 + ln]);
        v = max4(v, lds4[((2 * 4 + k) * 2 + lr) * 50 + ln]);
        v = max4(v, lds4[((3 * 4 + k) * 2 + lr) * 50 + ln]);
        int m = pg * 4 + k;
        if (m < NI) {
            float* pp = poolp + (((size_t)jc * B + b) * 256 + m) * 400 + lr * 200 + ln * 4;
            *(float4*)pp = v;
        }
    }
}

// ---------------- E: pooling phase B (combine 2 jc slices) ----------------
__global__ __launch_bounds__(256) void k_poolred(const float* __restrict__ poolp,
                                                 float* __restrict__ pool) {
    int idx = blockIdx.x * 256 + threadIdx.x;
    const int total = B * NI * 400;                // 812800
    if (idx >= total) return;
    int f = idx % 400;
    int t = idx / 400;
    int m = t % NI;
    int b = t / NI;
    float v = fmaxf(poolp[(((size_t)0 * B + b) * 256 + m) * 400 + f],
                    poolp[(((size_t)1 * B + b) * 256 + m) * 400 + f]);
    pool[((size_t)b * NI + m) * 400 + f] = v;
}

// ---------------- F: FC split-K partials ----------------
__global__ __launch_bounds__(256) void k_fc1(const float* __restrict__ pool,
                                             const float* __restrict__ tokp,
                                             const float* __restrict__ fcWt,
                                             float* __restrict__ fcp) {
    int o = blockIdx.x * 256 + threadIdx.x;
    const int total = B * S * L;
    if (o >= total) return;
    int ks = blockIdx.y;
    int b = o / (S * L);
    int rem = o - b * (S * L);
    int s = rem / L;
    int l = rem - s * L;
    if (s == 0 || s == S - 1) return;
    int m = s - 1;

    int k0 = ks * 325, k1 = k0 + 325;
    const float* pl = pool + ((size_t)b * NI + m) * 400;
    const float* tk = tokp + ((size_t)b * 258 + m + 1) * 300;  // llf: 900 contiguous
    float a0 = 0.f, a1 = 0.f;

    int pe = (k1 < 400) ? k1 : 400;
#pragma unroll 4
    for (int k = k0; k < pe; ++k) {
        float w = fcWt[k * L + l];
        a0 += w * pl[k];
    }
    int ts = (k0 > 400) ? k0 : 400;
#pragma unroll 4
    for (int k = ts; k < k1; ++k) {
        float w = fcWt[k * L + l];
        a1 += w * tk[k - 400];
    }
    fcp[(size_t)ks * total + o] = a0 + a1;
}

// ---------------- G: FC combine + end padding ----------------
__global__ __launch_bounds__(256) void k_fc2(const float* __restrict__ fcp,
                                             const float* __restrict__ fcB,
                                             float* __restrict__ out) {
    int o = blockIdx.x * 256 + threadIdx.x;
    const int total = B * S * L;
    if (o >= total) return;
    int rem = o % (S * L);
    int s = rem / L;
    int l = rem - s * L;
    float val;
    if (s == 0 || s == S - 1) {
        val = (l == L - 1) ? 1.0f : 0.0f;
    } else {
        val = fcB[l];
#pragma unroll
        for (int ks = 0; ks < 4; ks++)
            val += fcp[(size_t)ks * total + o];
    }
    out[o] = val;
}

extern "C" void kernel_launch(void* const* d_in, const int* in_sizes, int n_in,
                              void* d_out, int out_size, void* d_ws, size_t ws_size,
                              hipStream_t stream) {
    const int*   ids      = (const int*)d_in[0];
    const float* word_emb = (const float*)d_in[1];
    const float* pf_emb   = (const float*)d_in[2];
    const float* conv_W   = (const float*)d_in[3];
    const float* conv_b   = (const float*)d_in[4];
    const float* fc_W     = (const float*)d_in[5];
    const float* fc_b     = (const float*)d_in[6];
    float* out = (float*)d_out;
    float* ws  = (float*)d_ws;

    float* tokp  = ws + TOKP_OFF;
    float* Wr2   = ws + WR2_OFF;
    float* fcWt  = ws + FCWT_OFF;
    float* ct    = ws + CT_OFF;
    float* pool  = ws + POOL_OFF;
    float* g     = ws + G_OFF;
    float* c0    = ws + C0_OFF;
    float* c255  = ws + C255_OFF;
    float* poolp = ws + POOLP_OFF;
    float* fcp   = ws + FCP_OFF;

    k_gather<<<605, 256, 0, stream>>>(ids, word_emb, tokp);
    k_prep<<<704, 256, 0, stream>>>(conv_W, fc_W, pf_emb, Wr2, fcWt, g, c0, c255);
    k_conv<<<256, 1024, 0, stream>>>(tokp, Wr2, conv_b, ct);
    k_poolA<<<dim3(64, 2, 8), 256, 0, stream>>>(ct, g, c0, c255, poolp);
    k_poolred<<<3175, 256, 0, stream>>>(poolp, pool);
    k_fc1<<<dim3(272, 4), 256, 0, stream>>>(pool, tokp, fcWt, fcp);
    k_fc2<<<272, 256, 0, stream>>>(fcp, fc_b, out);
}

// Round 4
// 151.439 us; speedup vs baseline: 2.2303x; 1.2089x over previous
//
#include <hip/hip_runtime.h>

#define E 300
#define P 5
#define H 200
#define S 256
#define L 34
#define B 8
#define NI 254   // pivot positions i = 1..254

// ---- bf16 MFMA fragment types (per guide §3, compile-verified form) ----
typedef __attribute__((ext_vector_type(8))) short short8;
typedef __attribute__((ext_vector_type(4))) float f32x4;

// ws layout (floats; all offsets/sizes multiple of 4 floats -> 16B aligned)
#define TOKB_OFF   0
#define TOKB_FL    309632            // 8*258*300 bf16 + 64 slack = 619264 bf16
#define WR3_OFF    (TOKB_OFF+TOKB_FL)    // 309632 ; Wr3[208][928] bf16
#define WR3_FL     96512
#define FCWB_OFF   (WR3_OFF+WR3_FL)      // 406144 ; fcWb[48][1344] bf16
#define FCWB_FL    32256
#define G_OFF      (FCWB_OFF+FCWB_FL)    // 438400 ; g[512][200] f32
#define G_FL       102400
#define C0_OFF     (G_OFF+G_FL)          // 540800
#define C0_FL      50800
#define C255_OFF   (C0_OFF+C0_FL)        // 591600
#define C255_FL    50800
#define CT_OFF     (C255_OFF+C255_FL)    // 642400 ; ct[b][j][h] f32
#define CT_FL      409600
#define POOLBF_OFF (CT_OFF+CT_FL)        // 1052000 ; poolbf[b][256][416] bf16
#define POOLBF_FL  425984                // 851968 bf16
#define FCP_OFF    (POOLBF_OFF+POOLBF_FL)// 1477984 ; fcp[2][B*256*48] f32
#define FCP_FL     196608
// total 1,674,592 floats = 6.7 MB

__device__ __forceinline__ unsigned short f2bf(float f) {
    unsigned u = __float_as_uint(f);
    unsigned r = (u + 0x7FFFu + ((u >> 16) & 1u)) >> 16;   // RNE
    return (unsigned short)r;
}
__device__ __forceinline__ short8 load_a8(const unsigned short* p) {
    short8 r;
    ((ushort4*)&r)[0] = *(const ushort4*)p;        // 8B-aligned
    ((ushort4*)&r)[1] = *(const ushort4*)(p + 4);
    return r;
}
__device__ __forceinline__ float4 add4(float4 a, float4 b) {
    return make_float4(a.x+b.x, a.y+b.y, a.z+b.z, a.w+b.w);
}
__device__ __forceinline__ float4 max4(float4 a, float4 b) {
    return make_float4(fmaxf(a.x,b.x), fmaxf(a.y,b.y), fmaxf(a.z,b.z), fmaxf(a.w,b.w));
}

// ---------------- A: embedding gather -> tokb bf16[b][258][300] (rows 0,257 zero) ----
__global__ __launch_bounds__(256) void k_gather(const int* __restrict__ ids,
                                                const float* __restrict__ we,
                                                unsigned short* __restrict__ tokb) {
    int idx = blockIdx.x * 256 + threadIdx.x;      // 4-elem group
    const int total = B * 258 * 75;                // 154800
    if (idx >= total) return;
    int row = idx / 75;
    int col = idx - row * 75;
    int b = row / 258;
    int r = row - b * 258;
    float4 v = make_float4(0.f, 0.f, 0.f, 0.f);
    if (r >= 1 && r <= 256) {
        int id = ids[b * S + (r - 1)];
        v = ((const float4*)we)[(size_t)id * 75 + col];
    }
    ushort4 o;
    o.x = f2bf(v.x); o.y = f2bf(v.y); o.z = f2bf(v.z); o.w = f2bf(v.w);
    *(ushort4*)(tokb + (size_t)row * 300 + col * 4) = o;
}

// ---------------- B: prep (bf16 weight repacks + conv_pf tables) ----------------
// Wr3[h][kk] = conv_W[h, e, r] bf16, kk = r*300+e, zero-padded to 208x928
// fcWb[l][c] bf16: c<400 -> fc_W[l][c]; 416..1315 -> fc_W[l][400+(c-416)]; else 0
__global__ __launch_bounds__(256) void k_prep(const float* __restrict__ convW,
                                              const float* __restrict__ fcW,
                                              const float* __restrict__ pf,
                                              unsigned short* __restrict__ Wr3,
                                              unsigned short* __restrict__ fcWb,
                                              float* __restrict__ g,
                                              float* __restrict__ c0,
                                              float* __restrict__ c255) {
    int idx = blockIdx.x * 256 + threadIdx.x;
    if (idx < 193024) {                            // Wr3: 208*928
        int hh = idx / 928, kk = idx - hh * 928;
        float v = 0.f;
        if (hh < H && kk < 900) {
            int r = kk / 300, e = kk - r * 300;
            v = convW[hh * 915 + e * 3 + r];
        }
        Wr3[idx] = f2bf(v);
    } else if (idx < 257536) {                     // fcWb: 48*1344
        int t = idx - 193024;
        int l = t / 1344, c = t - l * 1344;
        float v = 0.f;
        if (l < L) {
            if (c < 400) v = fcW[l * 1300 + c];
            else if (c >= 416 && c < 1316) v = fcW[l * 1300 + 400 + (c - 416)];
        }
        fcWb[t] = f2bf(v);
    } else if (idx < 359936) {                     // g[t2][h]
        int t = idx - 257536;
        int t2 = t / H, h = t - t2 * H;
        int d = t2 - 256;
        float a = 0.f;
#pragma unroll
        for (int k = 0; k < 3; k++) {
            int r = d + k - 1; r = (r < 0) ? -r : r; if (r > 255) r = 255;
#pragma unroll
            for (int q = 0; q < P; q++)
                a += convW[h * 915 + (E + q) * 3 + k] * pf[r * P + q];
        }
        g[t] = a;
    } else if (idx < 410736) {                     // c0: j=0, tap k=0 dropped
        int t = idx - 359936;
        int m = t / H, h = t - m * H;
        int i = m + 1;
        float a = 0.f;
#pragma unroll
        for (int q = 0; q < P; q++) {
            a += convW[h * 915 + (E + q) * 3 + 1] * pf[i * P + q];
            a += convW[h * 915 + (E + q) * 3 + 2] * pf[(i - 1) * P + q];
        }
        c0[m * H + h] = a;
    } else if (idx < 461536) {                     // c255: j=255, tap k=2 dropped
        int t = idx - 410736;
        int m = t / H, h = t - m * H;
        int i = m + 1;
        float a = 0.f;
#pragma unroll
        for (int q = 0; q < P; q++) {
            a += convW[h * 915 + (E + q) * 3 + 0] * pf[(254 - i) * P + q];
            a += convW[h * 915 + (E + q) * 3 + 1] * pf[(255 - i) * P + q];
        }
        c255[m * H + h] = a;
    }
}

// ---------------- C: conv_tok GEMM via bf16 MFMA -> ct[b][j][h] f32 ----------------
// M=2048 (b,j), N=208 (h pad), K=928 (pad; B-side zeros nullify A overreads).
// A row (b,j) = tokb + (b*258+j)*300 : 900 contiguous bf16 (3-row window).
// grid (13 n-tiles, 32 m-groups); block = 4 waves = 4 m-tiles of 16.
__global__ __launch_bounds__(256) void k_conv(const unsigned short* __restrict__ tokb,
                                              const unsigned short* __restrict__ Wr3,
                                              const float* __restrict__ convB,
                                              float* __restrict__ ct) {
    int n0 = blockIdx.x * 16;
    int mg = blockIdx.y;
    int wave = threadIdx.x >> 6;
    int lane = threadIdx.x & 63;
    int quad = lane >> 4;
    int lr = lane & 15;
    int mtile = mg * 4 + wave;
    int b = mtile >> 4;
    int j0 = (mtile & 15) << 4;

    const unsigned short* pa = tokb + ((size_t)(b * 258 + j0 + lr) * 300 + quad * 8);
    const unsigned short* pb = Wr3 + ((size_t)(n0 + lr) * 928 + quad * 8);

    f32x4 acc0 = {0.f, 0.f, 0.f, 0.f};
    f32x4 acc1 = {0.f, 0.f, 0.f, 0.f};
#pragma unroll
    for (int kk = 0; kk + 1 < 29; kk += 2) {
        short8 a0 = load_a8(pa + kk * 32);
        short8 b0 = *(const short8*)(pb + kk * 32);
        acc0 = __builtin_amdgcn_mfma_f32_16x16x32_bf16(a0, b0, acc0, 0, 0, 0);
        short8 a1 = load_a8(pa + kk * 32 + 32);
        short8 b1 = *(const short8*)(pb + kk * 32 + 32);
        acc1 = __builtin_amdgcn_mfma_f32_16x16x32_bf16(a1, b1, acc1, 0, 0, 0);
    }
    {   // tail kk=28
        short8 a0 = load_a8(pa + 28 * 32);
        short8 b0 = *(const short8*)(pb + 28 * 32);
        acc0 = __builtin_amdgcn_mfma_f32_16x16x32_bf16(a0, b0, acc0, 0, 0, 0);
    }
    int h = n0 + lr;
    if (h < H) {
        float bias = convB[h];
        float* cp = ct + ((size_t)(b * 256 + j0 + quad * 4) * 200 + h);
#pragma unroll
        for (int r = 0; r < 4; r++)
            cp[(size_t)r * 200] = acc0[r] + acc1[r] + bias;
    }
}

// ---------------- D: dynamic max pool -> poolbf bf16[b][256 rows][416] ----------------
// grid (64 pg, 8 b); 256 thr = 4 j-subs x 64 lanes (50 active, h=4*lane).
// Rolling g registers: 1 g load + 1 ct load per j. Row s=m+1; cols 400..415 zeroed.
__global__ __launch_bounds__(256) void k_poolA(const float* __restrict__ ct,
                                               const float* __restrict__ g,
                                               const float* __restrict__ c0,
                                               const float* __restrict__ c255,
                                               unsigned short* __restrict__ poolbf) {
    __shared__ float4 lds4[4 * 4 * 2 * 50];        // [sub][k][lr][lane] 25.6 KB
    int pg = blockIdx.x;
    int b  = blockIdx.y;
    int tid = threadIdx.x;
    int sub = tid >> 6;
    int lane = tid & 63;
    int p0 = pg * 4 + 1;                           // pivots p0..p0+3

    if (lane < 50) {
        int h = lane << 2;
        const float* ctb = ct + (size_t)b * S * H + h;
        const float* gb  = g + h;

        float4 aL0 = {0,0,0,0}, aL1 = aL0, aL2 = aL0, aL3 = aL0;
        float4 aR0 = aL0, aR1 = aL0, aR2 = aL0, aR3 = aL0;

        if (sub == 0) {                            // j = 0 special (always left)
            float4 c = *(const float4*)(ctb);
            int m = pg * 4;
            if (m + 0 < NI) aL0 = max4(aL0, add4(c, *(const float4*)(c0 + (m+0) * H + h)));
            if (m + 1 < NI) aL1 = max4(aL1, add4(c, *(const float4*)(c0 + (m+1) * H + h)));
            if (m + 2 < NI) aL2 = max4(aL2, add4(c, *(const float4*)(c0 + (m+2) * H + h)));
            if (m + 3 < NI) aL3 = max4(aL3, add4(c, *(const float4*)(c0 + (m+3) * H + h)));
        }
        if (sub == 3) {                            // j = 255 special (always right)
            float4 c = *(const float4*)(ctb + (size_t)255 * H);
            int m = pg * 4;
            if (m + 0 < NI) aR0 = max4(aR0, add4(c, *(const float4*)(c255 + (m+0) * H + h)));
            if (m + 1 < NI) aR1 = max4(aR1, add4(c, *(const float4*)(c255 + (m+1) * H + h)));
            if (m + 2 < NI) aR2 = max4(aR2, add4(c, *(const float4*)(c255 + (m+2) * H + h)));
            if (m + 3 < NI) aR3 = max4(aR3, add4(c, *(const float4*)(c255 + (m+3) * H + h)));
        }

        int js = (sub == 0) ? 1 : sub * 64;
        int je = (sub == 3) ? 254 : sub * 64 + 63;

        // rolling g: grk = g[(j - p0 - k + 256)*H + h]
        float4 gr0 = *(const float4*)(gb + (size_t)(js - p0 + 256) * H);
        float4 gr1 = *(const float4*)(gb + (size_t)(js - p0 + 255) * H);
        float4 gr2 = *(const float4*)(gb + (size_t)(js - p0 + 254) * H);
        float4 gr3 = *(const float4*)(gb + (size_t)(js - p0 + 253) * H);

        for (int j = js; j <= je; ++j) {
            float4 c = *(const float4*)(ctb + (size_t)j * H);
            float4 v0 = add4(c, gr0);
            float4 v1 = add4(c, gr1);
            float4 v2 = add4(c, gr2);
            float4 v3 = add4(c, gr3);
            if (j < p0)     aL0 = max4(aL0, v0); else aR0 = max4(aR0, v0);
            if (j < p0 + 1) aL1 = max4(aL1, v1); else aR1 = max4(aR1, v1);
            if (j < p0 + 2) aL2 = max4(aL2, v2); else aR2 = max4(aR2, v2);
            if (j < p0 + 3) aL3 = max4(aL3, v3); else aR3 = max4(aR3, v3);
            gr3 = gr2; gr2 = gr1; gr1 = gr0;
            gr0 = *(const float4*)(gb + (size_t)(j + 1 - p0 + 256) * H);
        }

        float4* lp = lds4 + ((sub * 4 + 0) * 2) * 50 + lane;
        lp[0]   = aL0; lp[50]  = aR0;
        lp[100] = aL1; lp[150] = aR1;
        lp[200] = aL2; lp[250] = aR2;
        lp[300] = aL3; lp[350] = aR3;
    }
    __syncthreads();

    for (int idx = tid; idx < 400; idx += 256) {
        int k = idx / 100;
        int r = idx - k * 100;
        int half = r / 50;
        int ln = r - half * 50;
        float4 v =          lds4[((0 * 4 + k) * 2 + half) * 50 + ln];
        v = max4(v,         lds4[((1 * 4 + k) * 2 + half) * 50 + ln]);
        v = max4(v,         lds4[((2 * 4 + k) * 2 + half) * 50 + ln]);
        v = max4(v,         lds4[((3 * 4 + k) * 2 + half) * 50 + ln]);
        int m = pg * 4 + k;
        if (m < NI) {
            ushort4 o;
            o.x = f2bf(v.x); o.y = f2bf(v.y); o.z = f2bf(v.z); o.w = f2bf(v.w);
            *(ushort4*)(poolbf + (size_t)(b * 256 + m + 1) * 416 + half * 200 + ln * 4) = o;
        }
    }
    for (int idx = tid; idx < 64; idx += 256) {    // zero K-pad cols 400..415
        int k = idx >> 4, c = idx & 15;
        int m = pg * 4 + k;
        if (m < NI) poolbf[(size_t)(b * 256 + m + 1) * 416 + 400 + c] = 0;
    }
}

// ---------------- E: FC GEMM via bf16 MFMA (2 K-parts) -> fcp f32 ----------------
// M=2048 (b,s), N=48 (l pad), K: part0 = pool (416), part1 = llf via tokb (928).
__global__ __launch_bounds__(256) void k_fc1(const unsigned short* __restrict__ poolbf,
                                             const unsigned short* __restrict__ tokb,
                                             const unsigned short* __restrict__ fcWb,
                                             float* __restrict__ fcp) {
    int n0 = blockIdx.x * 16;
    int mg = blockIdx.y;
    int part = blockIdx.z;
    int wave = threadIdx.x >> 6;
    int lane = threadIdx.x & 63;
    int quad = lane >> 4;
    int lr = lane & 15;
    int mtile = mg * 4 + wave;
    int b = mtile >> 4;
    int s0 = (mtile & 15) << 4;

    const unsigned short* pa;
    const unsigned short* pb;
    int iters;
    if (part == 0) {
        pa = poolbf + ((size_t)(b * 256 + s0 + lr) * 416 + quad * 8);
        pb = fcWb + ((size_t)(n0 + lr) * 1344 + quad * 8);
        iters = 13;
    } else {
        pa = tokb + ((size_t)(b * 258 + s0 + lr) * 300 + quad * 8);
        pb = fcWb + ((size_t)(n0 + lr) * 1344 + 416 + quad * 8);
        iters = 29;
    }

    f32x4 acc0 = {0.f, 0.f, 0.f, 0.f};
    f32x4 acc1 = {0.f, 0.f, 0.f, 0.f};
    int kk = 0;
#pragma unroll 4
    for (; kk + 1 < iters; kk += 2) {
        short8 a0 = load_a8(pa + kk * 32);
        short8 b0 = *(const short8*)(pb + kk * 32);
        acc0 = __builtin_amdgcn_mfma_f32_16x16x32_bf16(a0, b0, acc0, 0, 0, 0);
        short8 a1 = load_a8(pa + kk * 32 + 32);
        short8 b1 = *(const short8*)(pb + kk * 32 + 32);
        acc1 = __builtin_amdgcn_mfma_f32_16x16x32_bf16(a1, b1, acc1, 0, 0, 0);
    }
    {   // both 13 and 29 are odd: one tail
        short8 a0 = load_a8(pa + kk * 32);
        short8 b0 = *(const short8*)(pb + kk * 32);
        acc0 = __builtin_amdgcn_mfma_f32_16x16x32_bf16(a0, b0, acc0, 0, 0, 0);
    }

    float* op = fcp + (size_t)part * (B * 256 * 48)
                    + (size_t)(b * 256 + s0 + quad * 4) * 48 + n0 + lr;
#pragma unroll
    for (int r = 0; r < 4; r++)
        op[(size_t)r * 48] = acc0[r] + acc1[r];
}

// ---------------- F: FC epilogue (combine parts + bias + end padding) ----------------
__global__ __launch_bounds__(256) void k_fc2(const float* __restrict__ fcp,
                                             const float* __restrict__ fcB,
                                             float* __restrict__ out) {
    int o = blockIdx.x * 256 + threadIdx.x;
    const int total = B * S * L;                   // 69632
    if (o >= total) return;
    int b = o / (S * L);
    int rem = o - b * (S * L);
    int s = rem / L;
    int l = rem - s * L;
    float val;
    if (s == 0 || s == S - 1) {
        val = (l == L - 1) ? 1.0f : 0.0f;
    } else {
        int rowoff = (b * 256 + s) * 48 + l;
        val = fcB[l] + fcp[rowoff] + fcp[(size_t)(B * 256 * 48) + rowoff];
    }
    out[o] = val;
}

extern "C" void kernel_launch(void* const* d_in, const int* in_sizes, int n_in,
                              void* d_out, int out_size, void* d_ws, size_t ws_size,
                              hipStream_t stream) {
    const int*   ids      = (const int*)d_in[0];
    const float* word_emb = (const float*)d_in[1];
    const float* pf_emb   = (const float*)d_in[2];
    const float* conv_W   = (const float*)d_in[3];
    const float* conv_b   = (const float*)d_in[4];
    const float* fc_W     = (const float*)d_in[5];
    const float* fc_b     = (const float*)d_in[6];
    float* out = (float*)d_out;
    float* ws  = (float*)d_ws;

    unsigned short* tokb   = (unsigned short*)(ws + TOKB_OFF);
    unsigned short* Wr3    = (unsigned short*)(ws + WR3_OFF);
    unsigned short* fcWb   = (unsigned short*)(ws + FCWB_OFF);
    float* g     = ws + G_OFF;
    float* c0    = ws + C0_OFF;
    float* c255  = ws + C255_OFF;
    float* ct    = ws + CT_OFF;
    unsigned short* poolbf = (unsigned short*)(ws + POOLBF_OFF);
    float* fcp   = ws + FCP_OFF;

    k_gather<<<605, 256, 0, stream>>>(ids, word_emb, tokb);
    k_prep<<<1803, 256, 0, stream>>>(conv_W, fc_W, pf_emb, Wr3, fcWb, g, c0, c255);
    k_conv<<<dim3(13, 32), 256, 0, stream>>>(tokb, Wr3, conv_b, ct);
    k_poolA<<<dim3(64, 8), 256, 0, stream>>>(ct, g, c0, c255, poolbf);
    k_fc1<<<dim3(3, 32, 2), 256, 0, stream>>>(poolbf, tokb, fcWb, fcp);
    k_fc2<<<272, 256, 0, stream>>>(fcp, fc_b, out);
}

// Round 5
// 133.700 us; speedup vs baseline: 2.5262x; 1.1327x over previous
//
#include <hip/hip_runtime.h>

#define E 300
#define P 5
#define H 200
#define S 256
#define L 34
#define B 8
#define NI 254   // pivot positions i = 1..254

typedef __attribute__((ext_vector_type(8))) short short8;
typedef __attribute__((ext_vector_type(4))) float f32x4;

// ws layout (floats; 16B-aligned offsets)
#define TOKB_OFF   0
#define TOKB_FL    309632                 // 8*258*300 bf16 + 64 slack (A-overread pad)
#define WR3_OFF    (TOKB_OFF+TOKB_FL)    // Wr3[208][928] bf16
#define WR3_FL     96512
#define FCWB_OFF   (WR3_OFF+WR3_FL)      // fcWb[48][1344] bf16
#define FCWB_FL    32256
#define G_OFF      (FCWB_OFF+FCWB_FL)    // g[512][200] f32
#define G_FL       102400
#define C0_OFF     (G_OFF+G_FL)
#define C0_FL      50800
#define C255_OFF   (C0_OFF+C0_FL)
#define C255_FL    50800
#define CT_OFF     (C255_OFF+C255_FL)    // ct[b][j][h] f32
#define CT_FL      409600
#define POOLBF_OFF (CT_OFF+CT_FL)        // poolbf[b][256][416] bf16
#define POOLBF_FL  425984
// total 1,477,984 floats = 5.9 MB

__device__ __forceinline__ unsigned short f2bf(float f) {
    unsigned u = __float_as_uint(f);
    unsigned r = (u + 0x7FFFu + ((u >> 16) & 1u)) >> 16;   // RNE
    return (unsigned short)r;
}
__device__ __forceinline__ short8 load_a8(const unsigned short* p) {
    short8 r;
    ((ushort4*)&r)[0] = *(const ushort4*)p;        // 8B-aligned
    ((ushort4*)&r)[1] = *(const ushort4*)(p + 4);
    return r;
}
__device__ __forceinline__ float4 add4(float4 a, float4 b) {
    return make_float4(a.x+b.x, a.y+b.y, a.z+b.z, a.w+b.w);
}
__device__ __forceinline__ float4 max4(float4 a, float4 b) {
    return make_float4(fmaxf(a.x,b.x), fmaxf(a.y,b.y), fmaxf(a.z,b.z), fmaxf(a.w,b.w));
}

#define GA_BLOCKS 605    // gather part: 154800 float4-groups
#define PREP_BLOCKS 1803 // prep part: 461536 items

// ---------------- A: fused init = embedding gather + weight repacks + pf tables ----
__global__ __launch_bounds__(256) void k_init(const int* __restrict__ ids,
                                              const float* __restrict__ we,
                                              const float* __restrict__ convW,
                                              const float* __restrict__ fcW,
                                              const float* __restrict__ pf,
                                              unsigned short* __restrict__ tokb,
                                              unsigned short* __restrict__ Wr3,
                                              unsigned short* __restrict__ fcWb,
                                              float* __restrict__ g,
                                              float* __restrict__ c0,
                                              float* __restrict__ c255) {
    if (blockIdx.x < GA_BLOCKS) {
        // tokb bf16[b][258][300], rows 0 & 257 zero
        int idx = blockIdx.x * 256 + threadIdx.x;
        const int total = B * 258 * 75;
        if (idx >= total) return;
        int row = idx / 75;
        int col = idx - row * 75;
        int b = row / 258;
        int r = row - b * 258;
        float4 v = make_float4(0.f, 0.f, 0.f, 0.f);
        if (r >= 1 && r <= 256) {
            int id = ids[b * S + (r - 1)];
            v = ((const float4*)we)[(size_t)id * 75 + col];
        }
        ushort4 o;
        o.x = f2bf(v.x); o.y = f2bf(v.y); o.z = f2bf(v.z); o.w = f2bf(v.w);
        *(ushort4*)(tokb + (size_t)row * 300 + col * 4) = o;
        return;
    }
    int idx = (blockIdx.x - GA_BLOCKS) * 256 + threadIdx.x;
    if (idx < 193024) {                            // Wr3: 208x928, Wr3[h][r*300+e]
        int hh = idx / 928, kk = idx - hh * 928;
        float v = 0.f;
        if (hh < H && kk < 900) {
            int r = kk / 300, e = kk - r * 300;
            v = convW[hh * 915 + e * 3 + r];
        }
        Wr3[idx] = f2bf(v);
    } else if (idx < 257536) {                     // fcWb: 48x1344
        int t = idx - 193024;
        int l = t / 1344, c = t - l * 1344;
        float v = 0.f;
        if (l < L) {
            if (c < 400) v = fcW[l * 1300 + c];
            else if (c >= 416 && c < 1316) v = fcW[l * 1300 + 400 + (c - 416)];
        }
        fcWb[t] = f2bf(v);
    } else if (idx < 359936) {                     // g[t2][h], t2 = (j-i)+256
        int t = idx - 257536;
        int t2 = t / H, h = t - t2 * H;
        int d = t2 - 256;
        float a = 0.f;
#pragma unroll
        for (int k = 0; k < 3; k++) {
            int r = d + k - 1; r = (r < 0) ? -r : r; if (r > 255) r = 255;
#pragma unroll
            for (int q = 0; q < P; q++)
                a += convW[h * 915 + (E + q) * 3 + k] * pf[r * P + q];
        }
        g[t] = a;
    } else if (idx < 410736) {                     // c0: j=0, tap k=0 dropped
        int t = idx - 359936;
        int m = t / H, h = t - m * H;
        int i = m + 1;
        float a = 0.f;
#pragma unroll
        for (int q = 0; q < P; q++) {
            a += convW[h * 915 + (E + q) * 3 + 1] * pf[i * P + q];
            a += convW[h * 915 + (E + q) * 3 + 2] * pf[(i - 1) * P + q];
        }
        c0[m * H + h] = a;
    } else if (idx < 461536) {                     // c255: j=255, tap k=2 dropped
        int t = idx - 410736;
        int m = t / H, h = t - m * H;
        int i = m + 1;
        float a = 0.f;
#pragma unroll
        for (int q = 0; q < P; q++) {
            a += convW[h * 915 + (E + q) * 3 + 0] * pf[(254 - i) * P + q];
            a += convW[h * 915 + (E + q) * 3 + 1] * pf[(255 - i) * P + q];
        }
        c255[m * H + h] = a;
    }
}

// ---------------- B: conv_tok GEMM via bf16 MFMA -> ct[b][j][h] f32 ----------------
// M=2048 (b,j), N=208 (h pad), K=928 (pad; zero B cols nullify A overreads).
__global__ __launch_bounds__(256) void k_conv(const unsigned short* __restrict__ tokb,
                                              const unsigned short* __restrict__ Wr3,
                                              const float* __restrict__ convB,
                                              float* __restrict__ ct) {
    int n0 = blockIdx.x * 16;
    int mg = blockIdx.y;
    int wave = threadIdx.x >> 6;
    int lane = threadIdx.x & 63;
    int quad = lane >> 4;
    int lr = lane & 15;
    int mtile = mg * 4 + wave;
    int b = mtile >> 4;
    int j0 = (mtile & 15) << 4;

    const unsigned short* pa = tokb + ((size_t)(b * 258 + j0 + lr) * 300 + quad * 8);
    const unsigned short* pb = Wr3 + ((size_t)(n0 + lr) * 928 + quad * 8);

    f32x4 acc0 = {0.f, 0.f, 0.f, 0.f};
    f32x4 acc1 = {0.f, 0.f, 0.f, 0.f};
#pragma unroll
    for (int kk = 0; kk + 1 < 29; kk += 2) {
        short8 a0 = load_a8(pa + kk * 32);
        short8 b0 = *(const short8*)(pb + kk * 32);
        acc0 = __builtin_amdgcn_mfma_f32_16x16x32_bf16(a0, b0, acc0, 0, 0, 0);
        short8 a1 = load_a8(pa + kk * 32 + 32);
        short8 b1 = *(const short8*)(pb + kk * 32 + 32);
        acc1 = __builtin_amdgcn_mfma_f32_16x16x32_bf16(a1, b1, acc1, 0, 0, 0);
    }
    {   // tail kk=28
        short8 a0 = load_a8(pa + 28 * 32);
        short8 b0 = *(const short8*)(pb + 28 * 32);
        acc0 = __builtin_amdgcn_mfma_f32_16x16x32_bf16(a0, b0, acc0, 0, 0, 0);
    }
    int h = n0 + lr;
    if (h < H) {
        float bias = convB[h];
        float* cp = ct + ((size_t)(b * 256 + j0 + quad * 4) * 200 + h);
#pragma unroll
        for (int r = 0; r < 4; r++)
            cp[(size_t)r * 200] = acc0[r] + acc1[r] + bias;
    }
}

// ---------------- C: dynamic max pool -> poolbf bf16[b][256 rows][416] ----------------
// grid (64 pg, 8 b); 512 thr = 8 j-subs x 64 lanes (50 active, h=4*lane), 32 j each.
// 16 waves/CU nominal (~50% occupancy). Rolling g regs, unroll-4 for renaming.
__global__ __launch_bounds__(512) void k_poolA(const float* __restrict__ ct,
                                               const float* __restrict__ g,
                                               const float* __restrict__ c0,
                                               const float* __restrict__ c255,
                                               unsigned short* __restrict__ poolbf) {
    __shared__ float4 lds4[8 * 4 * 2 * 50];        // [sub][k][lr][lane] 51.2 KB
    int pg = blockIdx.x;
    int b  = blockIdx.y;
    int tid = threadIdx.x;
    int sub = tid >> 6;
    int lane = tid & 63;
    int p0 = pg * 4 + 1;                           // pivots p0..p0+3

    if (lane < 50) {
        int h = lane << 2;
        const float* ctb = ct + (size_t)b * S * H + h;
        const float* gb  = g + h;

        float4 aL0 = {0,0,0,0}, aL1 = aL0, aL2 = aL0, aL3 = aL0;
        float4 aR0 = aL0, aR1 = aL0, aR2 = aL0, aR3 = aL0;

        if (sub == 0) {                            // j = 0 special (always left)
            float4 c = *(const float4*)(ctb);
            int m = pg * 4;
            if (m + 0 < NI) aL0 = max4(aL0, add4(c, *(const float4*)(c0 + (m+0) * H + h)));
            if (m + 1 < NI) aL1 = max4(aL1, add4(c, *(const float4*)(c0 + (m+1) * H + h)));
            if (m + 2 < NI) aL2 = max4(aL2, add4(c, *(const float4*)(c0 + (m+2) * H + h)));
            if (m + 3 < NI) aL3 = max4(aL3, add4(c, *(const float4*)(c0 + (m+3) * H + h)));
        }
        if (sub == 7) {                            // j = 255 special (always right)
            float4 c = *(const float4*)(ctb + (size_t)255 * H);
            int m = pg * 4;
            if (m + 0 < NI) aR0 = max4(aR0, add4(c, *(const float4*)(c255 + (m+0) * H + h)));
            if (m + 1 < NI) aR1 = max4(aR1, add4(c, *(const float4*)(c255 + (m+1) * H + h)));
            if (m + 2 < NI) aR2 = max4(aR2, add4(c, *(const float4*)(c255 + (m+2) * H + h)));
            if (m + 3 < NI) aR3 = max4(aR3, add4(c, *(const float4*)(c255 + (m+3) * H + h)));
        }

        int js = (sub == 0) ? 1 : sub * 32;
        int je = (sub == 7) ? 254 : sub * 32 + 31;

        float4 gr0 = *(const float4*)(gb + (size_t)(js - p0 + 256) * H);
        float4 gr1 = *(const float4*)(gb + (size_t)(js - p0 + 255) * H);
        float4 gr2 = *(const float4*)(gb + (size_t)(js - p0 + 254) * H);
        float4 gr3 = *(const float4*)(gb + (size_t)(js - p0 + 253) * H);

#pragma unroll 4
        for (int j = js; j <= je; ++j) {
            float4 c = *(const float4*)(ctb + (size_t)j * H);
            float4 v0 = add4(c, gr0);
            float4 v1 = add4(c, gr1);
            float4 v2 = add4(c, gr2);
            float4 v3 = add4(c, gr3);
            if (j < p0)     aL0 = max4(aL0, v0); else aR0 = max4(aR0, v0);
            if (j < p0 + 1) aL1 = max4(aL1, v1); else aR1 = max4(aR1, v1);
            if (j < p0 + 2) aL2 = max4(aL2, v2); else aR2 = max4(aR2, v2);
            if (j < p0 + 3) aL3 = max4(aL3, v3); else aR3 = max4(aR3, v3);
            gr3 = gr2; gr2 = gr1; gr1 = gr0;
            gr0 = *(const float4*)(gb + (size_t)(j + 1 - p0 + 256) * H);
        }

        float4* lp = lds4 + (size_t)sub * 400 + lane;
        lp[0]   = aL0; lp[50]  = aR0;
        lp[100] = aL1; lp[150] = aR1;
        lp[200] = aL2; lp[250] = aR2;
        lp[300] = aL3; lp[350] = aR3;
    }
    __syncthreads();

    if (tid < 400) {
        int k = tid / 100;
        int r = tid - k * 100;
        int half = r / 50;
        int ln = r - half * 50;
        int slot = (k * 2 + half) * 50 + ln;
        float4 v = lds4[slot];
#pragma unroll
        for (int s2 = 1; s2 < 8; s2++) v = max4(v, lds4[s2 * 400 + slot]);
        int m = pg * 4 + k;
        if (m < NI) {
            ushort4 o;
            o.x = f2bf(v.x); o.y = f2bf(v.y); o.z = f2bf(v.z); o.w = f2bf(v.w);
            *(ushort4*)(poolbf + (size_t)(b * 256 + m + 1) * 416 + half * 200 + ln * 4) = o;
        }
    } else if (tid < 464) {                        // zero K-pad cols 400..415
        int t = tid - 400;
        int k = t >> 4, c = t & 15;
        int m = pg * 4 + k;
        if (m < NI) poolbf[(size_t)(b * 256 + m + 1) * 416 + 400 + c] = 0;
    }
}

// ---------------- D: fused FC GEMM (both K-parts) + bias + end padding -> out ------
// M=2048 (b,s), N=48 (l pad). K part0 = pool (416), part1 = llf via tokb (928).
// Rows s=0,255 are garbage in A; overridden by the pad in the epilogue.
__global__ __launch_bounds__(256) void k_fc(const unsigned short* __restrict__ poolbf,
                                            const unsigned short* __restrict__ tokb,
                                            const unsigned short* __restrict__ fcWb,
                                            const float* __restrict__ fcB,
                                            float* __restrict__ out) {
    int n0 = blockIdx.x * 16;
    int mg = blockIdx.y;
    int wave = threadIdx.x >> 6;
    int lane = threadIdx.x & 63;
    int quad = lane >> 4;
    int lr = lane & 15;
    int mtile = mg * 4 + wave;
    int b = mtile >> 4;
    int s0 = (mtile & 15) << 4;

    const unsigned short* pa0 = poolbf + ((size_t)(b * 256 + s0 + lr) * 416 + quad * 8);
    const unsigned short* pa1 = tokb + ((size_t)(b * 258 + s0 + lr) * 300 + quad * 8);
    const unsigned short* pb0 = fcWb + ((size_t)(n0 + lr) * 1344 + quad * 8);
    const unsigned short* pb1 = pb0 + 416;

    f32x4 acc0 = {0.f, 0.f, 0.f, 0.f};
    f32x4 acc1 = {0.f, 0.f, 0.f, 0.f};
    int kk = 0;
#pragma unroll 3
    for (kk = 0; kk + 1 < 13; kk += 2) {
        short8 a0 = load_a8(pa0 + kk * 32);
        short8 b0 = *(const short8*)(pb0 + kk * 32);
        acc0 = __builtin_amdgcn_mfma_f32_16x16x32_bf16(a0, b0, acc0, 0, 0, 0);
        short8 a1 = load_a8(pa0 + kk * 32 + 32);
        short8 b1 = *(const short8*)(pb0 + kk * 32 + 32);
        acc1 = __builtin_amdgcn_mfma_f32_16x16x32_bf16(a1, b1, acc1, 0, 0, 0);
    }
    {   // part0 tail kk=12
        short8 a0 = load_a8(pa0 + 12 * 32);
        short8 b0 = *(const short8*)(pb0 + 12 * 32);
        acc0 = __builtin_amdgcn_mfma_f32_16x16x32_bf16(a0, b0, acc0, 0, 0, 0);
    }
#pragma unroll 4
    for (kk = 0; kk + 1 < 29; kk += 2) {
        short8 a0 = load_a8(pa1 + kk * 32);
        short8 b0 = *(const short8*)(pb1 + kk * 32);
        acc0 = __builtin_amdgcn_mfma_f32_16x16x32_bf16(a0, b0, acc0, 0, 0, 0);
        short8 a1 = load_a8(pa1 + kk * 32 + 32);
        short8 b1 = *(const short8*)(pb1 + kk * 32 + 32);
        acc1 = __builtin_amdgcn_mfma_f32_16x16x32_bf16(a1, b1, acc1, 0, 0, 0);
    }
    {   // part1 tail kk=28
        short8 a0 = load_a8(pa1 + 28 * 32);
        short8 b0 = *(const short8*)(pb1 + 28 * 32);
        acc0 = __builtin_amdgcn_mfma_f32_16x16x32_bf16(a0, b0, acc0, 0, 0, 0);
    }

    int l = n0 + lr;
    if (l < L) {
        float bias = fcB[l];
#pragma unroll
        for (int r = 0; r < 4; r++) {
            int s = s0 + quad * 4 + r;
            float val;
            if (s == 0 || s == S - 1) val = (l == L - 1) ? 1.0f : 0.0f;
            else                      val = acc0[r] + acc1[r] + bias;
            out[(size_t)(b * 256 + s) * L + l] = val;
        }
    }
}

extern "C" void kernel_launch(void* const* d_in, const int* in_sizes, int n_in,
                              void* d_out, int out_size, void* d_ws, size_t ws_size,
                              hipStream_t stream) {
    const int*   ids      = (const int*)d_in[0];
    const float* word_emb = (const float*)d_in[1];
    const float* pf_emb   = (const float*)d_in[2];
    const float* conv_W   = (const float*)d_in[3];
    const float* conv_b   = (const float*)d_in[4];
    const float* fc_W     = (const float*)d_in[5];
    const float* fc_b     = (const float*)d_in[6];
    float* out = (float*)d_out;
    float* ws  = (float*)d_ws;

    unsigned short* tokb   = (unsigned short*)(ws + TOKB_OFF);
    unsigned short* Wr3    = (unsigned short*)(ws + WR3_OFF);
    unsigned short* fcWb   = (unsigned short*)(ws + FCWB_OFF);
    float* g     = ws + G_OFF;
    float* c0    = ws + C0_OFF;
    float* c255  = ws + C255_OFF;
    float* ct    = ws + CT_OFF;
    unsigned short* poolbf = (unsigned short*)(ws + POOLBF_OFF);

    k_init<<<GA_BLOCKS + PREP_BLOCKS, 256, 0, stream>>>(ids, word_emb, conv_W, fc_W,
                                                        pf_emb, tokb, Wr3, fcWb,
                                                        g, c0, c255);
    k_conv<<<dim3(13, 32), 256, 0, stream>>>(tokb, Wr3, conv_b, ct);
    k_poolA<<<dim3(64, 8), 512, 0, stream>>>(ct, g, c0, c255, poolbf);
    k_fc<<<dim3(3, 32), 256, 0, stream>>>(poolbf, tokb, fcWb, fc_b, out);
}